// Round 14
// baseline (1404.122 us; speedup 1.0000x reference)
//
#include <hip/hip_runtime.h>
#include <hip/hip_bf16.h>
#include <cstdint>
#include <cstddef>

// ---------------------------------------------------------------------------
// GPT-2-small forward on MI355X. bf16 MFMA GEMMs (f32 accum), f32 residual
// stream. Weights repacked bf16 TRANSPOSED ([N][K]).
// gemm_bt: 128x128 BK64 single-buffer, XOR swizzle, 4 blocks/CU (layer GEMMs).
// gemm_lm: 256x128 BK=32, 512 thr, 4 blocks/CU (was 2 at BK=64 — occupancy
//          40% was the binder), full-line NT f32x4 epilogue (r12/r13).
// attn   : block-cooperative K/V staging + causal load-balance qb swizzle.
// ---------------------------------------------------------------------------

typedef __bf16 bf16x8 __attribute__((ext_vector_type(8)));
typedef __bf16 bf16x4 __attribute__((ext_vector_type(4)));
typedef float  f32x4  __attribute__((ext_vector_type(4)));

#define MFMA16(a, b, c) __builtin_amdgcn_mfma_f32_16x16x32_bf16((a), (b), (c), 0, 0, 0)

__device__ __forceinline__ void g2l16(const void* g, void* l) {
    __builtin_amdgcn_global_load_lds(
        (const __attribute__((address_space(1))) void*)g,
        (__attribute__((address_space(3))) void*)l, 16, 0, 0);
}

// ---------------------------------------------------------------------------
// Weight repack: f32 [K,N] -> bf16 [N,K], 32x32 tiles, vectorized.
// ---------------------------------------------------------------------------
__global__ __launch_bounds__(256) void transpose_cvt(
    const float* __restrict__ src, __bf16* __restrict__ dst,
    int K, int N, int nNT)
{
    const float* s = src + (size_t)blockIdx.y * K * N;
    __bf16*      d = dst + (size_t)blockIdx.y * K * N;
    int kt = blockIdx.x / nNT, nt = blockIdx.x % nNT;
    int k0 = kt * 32, n0 = nt * 32;
    __shared__ float t[32][33];
    int rr = threadIdx.x >> 3, c4 = (threadIdx.x & 7) * 4;
    f32x4 v = *(const f32x4*)&s[(size_t)(k0 + rr) * N + n0 + c4];
#pragma unroll
    for (int j = 0; j < 4; j++) t[rr][c4 + j] = v[j];
    __syncthreads();
    bf16x4 ov;
#pragma unroll
    for (int j = 0; j < 4; j++) ov[j] = (__bf16)t[c4 + j][rr];
    *(bf16x4*)&d[(size_t)(n0 + rr) * K + k0 + c4] = ov;
}

// QKV gather-repack: Wq/Wk/Wv [L,H,768,64] f32 -> Wqkv_t [L][2304][768] bf16.
__global__ __launch_bounds__(256) void repack_qkv(
    const float* __restrict__ Wq, const float* __restrict__ Wk,
    const float* __restrict__ Wv, __bf16* __restrict__ dst)
{
    int l = blockIdx.z;
    int m = blockIdx.y / 12, h = blockIdx.y % 12;
    int kt = blockIdx.x / 2, nt = blockIdx.x % 2;
    const float* W = (m == 0 ? Wq : (m == 1 ? Wk : Wv)) + ((size_t)(l * 12 + h)) * 768 * 64;
    __bf16* d = dst + (size_t)l * 2304 * 768 + (size_t)(m * 768 + h * 64) * 768;
    int k0 = kt * 32, n0 = nt * 32;
    __shared__ float t[32][33];
    int rr = threadIdx.x >> 3, c4 = (threadIdx.x & 7) * 4;
    f32x4 v = *(const f32x4*)&W[(size_t)(k0 + rr) * 64 + n0 + c4];
#pragma unroll
    for (int j = 0; j < 4; j++) t[rr][c4 + j] = v[j];
    __syncthreads();
    bf16x4 ov;
#pragma unroll
    for (int j = 0; j < 4; j++) ov[j] = (__bf16)t[c4 + j][rr];
    *(bf16x4*)&d[(size_t)(n0 + rr) * 768 + k0 + c4] = ov;
}

// ---------------------------------------------------------------------------
// Embedding: wave-per-row, f32x4 vectorized.
// ---------------------------------------------------------------------------
__global__ __launch_bounds__(256) void embed_kernel(
    const int* __restrict__ idx, const float* __restrict__ tok,
    const float* __restrict__ pos, float* __restrict__ x)
{
    const int row = blockIdx.x * 4 + (threadIdx.x >> 6);
    const int lane = threadIdx.x & 63;
    int id = idx[row];
    const float* te = tok + (size_t)id * 768;
    const float* pe = pos + (size_t)(row & 1023) * 768;
    float* xr = x + (size_t)row * 768;
#pragma unroll
    for (int p = 0; p < 3; p++) {
        int c = p * 256 + lane * 4;
        f32x4 a = *(const f32x4*)&te[c];
        f32x4 b = *(const f32x4*)&pe[c];
        a[0] += b[0]; a[1] += b[1]; a[2] += b[2]; a[3] += b[3];
        *(f32x4*)&xr[c] = a;
    }
}

// ---------------------------------------------------------------------------
// LayerNorm: wave-per-row, f32x4 loads, bf16x4 stores, shuffle-only reduce.
// ---------------------------------------------------------------------------
__global__ __launch_bounds__(256) void ln_kernel(
    const float* __restrict__ x, const float* __restrict__ g,
    const float* __restrict__ bb, __bf16* __restrict__ out)
{
    const int row = blockIdx.x * 4 + (threadIdx.x >> 6);
    const int lane = threadIdx.x & 63;
    const float* xr = x + (size_t)row * 768;
    f32x4 v[3];
    float s = 0.f, s2 = 0.f;
#pragma unroll
    for (int p = 0; p < 3; p++) {
        v[p] = *(const f32x4*)&xr[p * 256 + lane * 4];
#pragma unroll
        for (int j = 0; j < 4; j++) { s += v[p][j]; s2 += v[p][j] * v[p][j]; }
    }
#pragma unroll
    for (int d = 1; d < 64; d <<= 1) {
        s  += __shfl_xor(s, d);
        s2 += __shfl_xor(s2, d);
    }
    float mean = s * (1.f / 768.f);
    float var  = s2 * (1.f / 768.f) - mean * mean;
    float rstd = rsqrtf(var + 1e-5f);
    __bf16* orow = out + (size_t)row * 768;
#pragma unroll
    for (int p = 0; p < 3; p++) {
        int c = p * 256 + lane * 4;
        f32x4 gg = *(const f32x4*)&g[c];
        f32x4 bv = *(const f32x4*)&bb[c];
        bf16x4 ov;
#pragma unroll
        for (int j = 0; j < 4; j++)
            ov[j] = (__bf16)((v[p][j] - mean) * rstd * gg[j] + bv[j]);
        *(bf16x4*)&orow[c] = ov;
    }
}

// ---------------------------------------------------------------------------
// gemm_bt: 128x128 tile, BK=64, 4 waves, single-buffered 32KB LDS, XOR chunk
// swizzle (0 conflicts), (256,4) — best measured config for layer GEMMs.
// ---------------------------------------------------------------------------
template <int RELU, int BIAS, int RES, int OBF16, int VT>
__global__ __launch_bounds__(256, 4) void gemm_bt(
    const __bf16* __restrict__ A, const __bf16* __restrict__ Bt,
    const float* __restrict__ bias, const float* __restrict__ res,
    void* __restrict__ Cout, __bf16* __restrict__ vt, int M, int N, int K)
{
    __shared__ __bf16 As[128 * 64];
    __shared__ __bf16 Bs[128 * 64];
    const int tid = threadIdx.x;
    const int w = tid >> 6, lane = tid & 63, lr = lane & 15, lg = lane >> 4;
    const int wr = w >> 1, wc = w & 1;

    const int MT  = gridDim.y;
    const int nwg = gridDim.x * gridDim.y;
    const int ord = blockIdx.y * gridDim.x + blockIdx.x;
    const int qq = nwg >> 3, rm = nwg & 7;
    const int xcd = ord & 7, pos = ord >> 3;
    const int wgid = (xcd < rm ? xcd * (qq + 1) : rm * (qq + 1) + (xcd - rm) * qq) + pos;
    const int m0 = (wgid % MT) * 128, n0 = (wgid / MT) * 128;

    f32x4 acc[4][4];
#pragma unroll
    for (int i = 0; i < 4; i++)
#pragma unroll
        for (int j = 0; j < 4; j++) acc[i][j] = (f32x4){0.f, 0.f, 0.f, 0.f};

    const __bf16* Abase = A  + (size_t)m0 * K;
    const __bf16* Bbase = Bt + (size_t)n0 * K;

    for (int k0 = 0; k0 < K; k0 += 64) {
#pragma unroll
        for (int u = 0; u < 4; ++u) {
            int chunk = u * 256 + tid;
            int rr = chunk >> 3, cc = chunk & 7;
            int se = (cc ^ (rr & 7)) << 3;
            g2l16(Abase + (size_t)rr * K + k0 + se, (char*)As + chunk * 16);
            g2l16(Bbase + (size_t)rr * K + k0 + se, (char*)Bs + chunk * 16);
        }
        __syncthreads();
#pragma unroll
        for (int ks = 0; ks < 2; ++ks) {
            bf16x8 af[4], bfv[4];
#pragma unroll
            for (int i = 0; i < 4; ++i) {
                int ra = wr * 64 + i * 16 + lr;
                af[i]  = *(const bf16x8*)((const char*)As + ra * 128 + (((ks * 4 + lg) ^ (ra & 7)) << 4));
                int rb = wc * 64 + i * 16 + lr;
                bfv[i] = *(const bf16x8*)((const char*)Bs + rb * 128 + (((ks * 4 + lg) ^ (rb & 7)) << 4));
            }
#pragma unroll
            for (int i = 0; i < 4; ++i)
#pragma unroll
                for (int j = 0; j < 4; ++j)
                    acc[i][j] = MFMA16(af[i], bfv[j], acc[i][j]);
        }
        __syncthreads();
    }

    const bool isv = VT && (n0 >= 1536);
#pragma unroll
    for (int i = 0; i < 4; i++) {
        int row = m0 + wr * 64 + i * 16 + lg * 4;
#pragma unroll
        for (int j = 0; j < 4; j++) {
            int col = n0 + wc * 64 + j * 16 + lr;
            if (isv) {   // write V transposed: vt[(b*12+h)*64+hs][t]
                int bb = row >> 10, tl = row & 1023;
                int vrow = (bb * 12 + ((col - 1536) >> 6)) * 64 + (col & 63);
                bf16x4 pv;
#pragma unroll
                for (int rr = 0; rr < 4; ++rr) pv[rr] = (__bf16)(acc[i][j][rr]);
                *(bf16x4*)&vt[(size_t)vrow * 1024 + tl] = pv;
            } else {
                float bv = BIAS ? bias[col] : 0.f;
#pragma unroll
                for (int rr = 0; rr < 4; rr++) {
                    float v = acc[i][j][rr] + bv;
                    if (RES)  v += res[(size_t)(row + rr) * N + col];
                    if (RELU) v = fmaxf(v, 0.f);
                    if (OBF16) ((__bf16*)Cout)[(size_t)(row + rr) * N + col] = (__bf16)v;
                    else       ((float*)Cout)[(size_t)(row + rr) * N + col] = v;
                }
            }
        }
    }
}

// ---------------------------------------------------------------------------
// gemm_lm: 256x128 tile, BK=32, 512 threads (8 waves 4m x 2n, 64x64 each),
// single-buffered 24KB tile LDS (shared 36.9KB block incl. epilogue scratch),
// XOR swizzle (4 chunks/row -> cc^(rr&3)), 4 blocks/CU (launch_bounds(512,4):
// budget 128 >= 64 AGPR + ~60 VGPR). Occupancy 40->80%: 4 co-resident blocks
// cover the per-K-step vmcnt drain (the r13 binder). Full-line NT epilogue.
// ---------------------------------------------------------------------------
template <int BIAS>
__global__ __launch_bounds__(512, 4) void gemm_lm(
    const __bf16* __restrict__ A, const __bf16* __restrict__ Bt,
    const float* __restrict__ bias, float* __restrict__ C, int M, int N, int K)
{
    __shared__ __bf16 S[18432];                 // 36.9KB: tiles 24KB | epi scratch
    __bf16* As = S;                             // 256 rows x 32 = 16KB
    __bf16* Bs = S + 256 * 32;                  // 128 rows x 32 = 8KB
    const int tid = threadIdx.x;
    const int w = tid >> 6, lane = tid & 63, lr = lane & 15, lg = lane >> 4;
    const int wm = w >> 1, wn = w & 1;

    const int MT  = gridDim.y;
    const int nwg = gridDim.x * gridDim.y;
    const int ord = blockIdx.y * gridDim.x + blockIdx.x;
    const int qq = nwg >> 3, rm = nwg & 7;
    const int xcd = ord & 7, pos = ord >> 3;
    const int wgid = (xcd < rm ? xcd * (qq + 1) : rm * (qq + 1) + (xcd - rm) * qq) + pos;
    const int m0 = (wgid % MT) * 256, n0 = (wgid / MT) * 128;

    f32x4 acc[4][4];
#pragma unroll
    for (int i = 0; i < 4; i++)
#pragma unroll
        for (int j = 0; j < 4; j++) acc[i][j] = (f32x4){0.f, 0.f, 0.f, 0.f};

    const __bf16* Abase = A  + (size_t)m0 * K;
    const __bf16* Bbase = Bt + (size_t)n0 * K;

    for (int k0 = 0; k0 < K; k0 += 32) {
        // A: 1024 chunks (256 rows x 4), B: 512 chunks (128 rows x 4)
#pragma unroll
        for (int u = 0; u < 2; ++u) {
            int chunk = u * 512 + tid;
            int rr = chunk >> 2, cc = chunk & 3;
            g2l16(Abase + (size_t)rr * K + k0 + ((cc ^ (rr & 3)) << 3),
                  (char*)As + chunk * 16);
        }
        {
            int chunk = tid;
            int rr = chunk >> 2, cc = chunk & 3;
            g2l16(Bbase + (size_t)rr * K + k0 + ((cc ^ (rr & 3)) << 3),
                  (char*)Bs + chunk * 16);
        }
        __syncthreads();
        bf16x8 af[4], bfv[4];
#pragma unroll
        for (int i = 0; i < 4; ++i) {
            int ra = wm * 64 + i * 16 + lr;
            af[i]  = *(const bf16x8*)((const char*)As + ra * 64 + ((lg ^ (ra & 3)) << 4));
            int rb = wn * 64 + i * 16 + lr;
            bfv[i] = *(const bf16x8*)((const char*)Bs + rb * 64 + ((lg ^ (rb & 3)) << 4));
        }
#pragma unroll
        for (int i = 0; i < 4; ++i)
#pragma unroll
            for (int j = 0; j < 4; ++j)
                acc[i][j] = MFMA16(af[i], bfv[j], acc[i][j]);
        __syncthreads();
    }

    // ---- full-line NT epilogue: wave-private 16x72 f32 scratch ----
    float* wls = (float*)S + w * 1152;
    const int er = lane >> 4;                   // 4 rows per store instr
    const int ec = lane & 15;                   // 16 lanes x f32x4 = 2 full lines
    f32x4 bb4 = (f32x4){0.f, 0.f, 0.f, 0.f};
    if (BIAS) bb4 = *(const f32x4*)&bias[n0 + wn * 64 + ec * 4];
#pragma unroll
    for (int i = 0; i < 4; i++) {
#pragma unroll
        for (int j = 0; j < 4; j++)
#pragma unroll
            for (int rr = 0; rr < 4; rr++)
                wls[(lg * 4 + rr) * 72 + j * 16 + lr] = acc[i][j][rr];
#pragma unroll
        for (int t = 0; t < 4; t++) {
            int r16 = t * 4 + er;
            f32x4 v = *(const f32x4*)&wls[r16 * 72 + ec * 4];
            v[0] += bb4[0]; v[1] += bb4[1]; v[2] += bb4[2]; v[3] += bb4[3];
            int grow = m0 + wm * 64 + i * 16 + r16;
            __builtin_nontemporal_store(v, (f32x4*)(C + (size_t)grow * N + n0 + wn * 64 + ec * 4));
        }
    }
}

// ---------------------------------------------------------------------------
// Fused causal flash attention, block-cooperative K/V staging, fixed-max
// softmax (validated r5-r13). KVBLK=128, XOR-swizzled LDS, 3 blocks/CU,
// causal load-balance qb swizzle {x, 15-x, x^8} (r13, validated).
// ---------------------------------------------------------------------------
__global__ __launch_bounds__(256, 3) void attn_kernel(
    const __bf16* __restrict__ qkv, const __bf16* __restrict__ vt,
    __bf16* __restrict__ o)
{
    __shared__ __bf16 Kl[128 * 64];
    __shared__ __bf16 Vl[64 * 128];
    __shared__ __bf16 Pl[4][16][72];
    const int h = blockIdx.y, b = blockIdx.z;
    const int flat = blockIdx.x + 16 * (blockIdx.y + 12 * blockIdx.z);
    const int rch = flat >> 8;
    const int xq = blockIdx.x;
    const int qb = (rch == 0) ? xq : (rch == 1 ? 15 - xq : (xq ^ 8));
    const int tid = threadIdx.x, w = tid >> 6, lane = tid & 63, lr = lane & 15, lg = lane >> 4;
    const int q0 = qb * 64 + w * 16;
    const size_t rowb = (size_t)b * 1024;
    const __bf16* Kg = qkv + rowb * 2304 + 768 + (size_t)h * 64;
    const __bf16* Vg = vt + (size_t)(b * 12 + h) * 64 * 1024;

    bf16x8 qf[2];
    {
        const __bf16* qp = qkv + (rowb + q0 + lr) * 2304 + h * 64 + lg * 8;
        qf[0] = *(const bf16x8*)qp;
        qf[1] = *(const bf16x8*)(qp + 32);
    }

    f32x4 oacc[4];
#pragma unroll
    for (int i = 0; i < 4; i++) oacc[i] = (f32x4){0.f, 0.f, 0.f, 0.f};
    float lpart[4] = {0.f, 0.f, 0.f, 0.f};

    const int nkb = (qb >> 1) + 1;
    for (int kb = 0; kb < nkb; ++kb) {
        __syncthreads();
#pragma unroll
        for (int u = 0; u < 4; ++u) {
            int chunk = u * 256 + tid;
            int kr = chunk >> 3, cc = chunk & 7;
            g2l16(Kg + (size_t)(kb * 128 + kr) * 2304 + ((cc ^ (kr & 7)) << 3),
                  (char*)Kl + chunk * 16);
        }
#pragma unroll
        for (int u = 0; u < 4; ++u) {
            int chunk = u * 256 + tid;
            int vr = chunk >> 4, cc = chunk & 15;
            g2l16(Vg + (size_t)vr * 1024 + kb * 128 + ((cc ^ (vr & 15)) << 3),
                  (char*)Vl + chunk * 16);
        }
        __syncthreads();

#pragma unroll
        for (int hh = 0; hh < 2; ++hh) {
            if (kb * 128 + hh * 64 > q0 + 15) break;
            float e[4][4];
#pragma unroll
            for (int cb = 0; cb < 4; ++cb) {
                const int krow = hh * 64 + cb * 16 + lr;
                const int key  = kb * 128 + krow;
                bf16x8 k0 = *(const bf16x8*)((const char*)Kl + krow * 128 + ((lg ^ (krow & 7)) << 4));
                bf16x8 k1 = *(const bf16x8*)((const char*)Kl + krow * 128 + (((4 + lg) ^ (krow & 7)) << 4));
                f32x4 s = (f32x4){0.f, 0.f, 0.f, 0.f};
                s = MFMA16(qf[0], k0, s);
                s = MFMA16(qf[1], k1, s);
#pragma unroll
                for (int rr = 0; rr < 4; rr++) {
                    int qrow = q0 + lg * 4 + rr;
                    float p = (key > qrow) ? -1e30f : s[rr] * 0.125f;
                    e[cb][rr] = __expf(p - 3.0f);
                }
            }
#pragma unroll
            for (int rr = 0; rr < 4; rr++) {
                lpart[rr] += (e[0][rr] + e[1][rr]) + (e[2][rr] + e[3][rr]);
                Pl[w][lg * 4 + rr][lr]      = (__bf16)e[0][rr];
                Pl[w][lg * 4 + rr][16 + lr] = (__bf16)e[1][rr];
                Pl[w][lg * 4 + rr][32 + lr] = (__bf16)e[2][rr];
                Pl[w][lg * 4 + rr][48 + lr] = (__bf16)e[3][rr];
            }
            bf16x8 pf0 = *(const bf16x8*)&Pl[w][lr][lg * 8];
            bf16x8 pf1 = *(const bf16x8*)&Pl[w][lr][32 + lg * 8];
#pragma unroll
            for (int nb = 0; nb < 4; nb++) {
                const int vrow = nb * 16 + lr;
                bf16x8 v0 = *(const bf16x8*)((const char*)Vl + vrow * 256 + (((hh * 8 + lg) ^ (vrow & 15)) << 4));
                bf16x8 v1 = *(const bf16x8*)((const char*)Vl + vrow * 256 + (((hh * 8 + 4 + lg) ^ (vrow & 15)) << 4));
                oacc[nb] = MFMA16(pf0, v0, oacc[nb]);
                oacc[nb] = MFMA16(pf1, v1, oacc[nb]);
            }
        }
    }

#pragma unroll
    for (int rr = 0; rr < 4; rr++) {
        float ls = lpart[rr];
        ls += __shfl_xor(ls, 1);
        ls += __shfl_xor(ls, 2);
        ls += __shfl_xor(ls, 4);
        ls += __shfl_xor(ls, 8);
        float inv = 1.0f / ls;
        size_t row = rowb + q0 + lg * 4 + rr;
#pragma unroll
        for (int nb = 0; nb < 4; nb++)
            o[row * 768 + h * 64 + nb * 16 + lr] = (__bf16)(oacc[nb][rr] * inv);
    }
}

// ---------------------------------------------------------------------------
extern "C" void kernel_launch(void* const* d_in, const int* in_sizes, int n_in,
                              void* d_out, int out_size, void* d_ws, size_t ws_size,
                              hipStream_t stream)
{
    (void)in_sizes; (void)n_in; (void)out_size; (void)ws_size;
    const int*   idx  = (const int*)d_in[0];
    const float* tok  = (const float*)d_in[1];
    const float* pos  = (const float*)d_in[2];
    const float* Wq   = (const float*)d_in[3];
    const float* Wk   = (const float*)d_in[4];
    const float* Wv   = (const float*)d_in[5];
    const float* Wp   = (const float*)d_in[6];
    const float* bp   = (const float*)d_in[7];
    const float* ln1g = (const float*)d_in[8];
    const float* ln1b = (const float*)d_in[9];
    const float* ln2g = (const float*)d_in[10];
    const float* ln2b = (const float*)d_in[11];
    const float* W1   = (const float*)d_in[12];
    const float* b1   = (const float*)d_in[13];
    const float* W2   = (const float*)d_in[14];
    const float* b2   = (const float*)d_in[15];
    const float* lnfg = (const float*)d_in[16];
    const float* lnfb = (const float*)d_in[17];
    const float* lmW  = (const float*)d_in[18];
    const float* lmb  = (const float*)d_in[19];

    char* ws = (char*)d_ws;
    size_t off = 0;
    auto alloc = [&](size_t bytes) {
        char* p = ws + off;
        off += (bytes + 255) & ~(size_t)255;
        return p;
    };
    __bf16* Wqkv_t = (__bf16*)alloc((size_t)6 * 2304 * 768 * 2);
    __bf16* Wp_t   = (__bf16*)alloc((size_t)6 * 768 * 768 * 2);
    __bf16* W1_t   = (__bf16*)alloc((size_t)6 * 3072 * 768 * 2);
    __bf16* W2_t   = (__bf16*)alloc((size_t)6 * 768 * 3072 * 2);
    __bf16* lm_t   = (__bf16*)alloc((size_t)32000 * 768 * 2);
    float*  x      = (float*)alloc((size_t)4096 * 768 * 4);
    __bf16* hbuf   = (__bf16*)alloc((size_t)4096 * 768 * 2);
    __bf16* qkv    = (__bf16*)alloc((size_t)4096 * 2304 * 2);
    __bf16* obuf   = (__bf16*)alloc((size_t)4096 * 768 * 2);
    __bf16* mlp    = (__bf16*)alloc((size_t)4096 * 3072 * 2);
    __bf16* vt     = mlp;   // lifetime-disjoint: vt used qkv->attn, mlp fc1->fc2

    // ---- weight repack (bf16, transposed) ----
    transpose_cvt<<<dim3(24 * 24, 6), 256, 0, stream>>>(Wp, Wp_t, 768, 768, 24);
    transpose_cvt<<<dim3(24 * 96, 6), 256, 0, stream>>>(W1, W1_t, 768, 3072, 96);
    transpose_cvt<<<dim3(96 * 24, 6), 256, 0, stream>>>(W2, W2_t, 3072, 768, 24);
    transpose_cvt<<<dim3(24 * 1000, 1), 256, 0, stream>>>(lmW, lm_t, 768, 32000, 1000);
    repack_qkv<<<dim3(48, 36, 6), 256, 0, stream>>>(Wq, Wk, Wv, Wqkv_t);

    // ---- forward ----
    embed_kernel<<<1024, 256, 0, stream>>>(idx, tok, pos, x);

    for (int l = 0; l < 6; l++) {
        ln_kernel<<<1024, 256, 0, stream>>>(x, ln1g + l * 768, ln1b + l * 768, hbuf);
        gemm_bt<0, 0, 0, 1, 1><<<dim3(18, 32), 256, 0, stream>>>(
            hbuf, Wqkv_t + (size_t)l * 2304 * 768, nullptr, nullptr, qkv, vt, 4096, 2304, 768);
        attn_kernel<<<dim3(16, 12, 4), 256, 0, stream>>>(qkv, vt, obuf);
        gemm_bt<0, 1, 1, 0, 0><<<dim3(6, 32), 256, 0, stream>>>(
            obuf, Wp_t + (size_t)l * 768 * 768, bp + l * 768, x, x, nullptr, 4096, 768, 768);
        ln_kernel<<<1024, 256, 0, stream>>>(x, ln2g + l * 768, ln2b + l * 768, hbuf);
        gemm_bt<1, 1, 0, 1, 0><<<dim3(24, 32), 256, 0, stream>>>(
            hbuf, W1_t + (size_t)l * 3072 * 768, b1 + l * 3072, nullptr, mlp, nullptr, 4096, 3072, 768);
        gemm_bt<0, 1, 1, 0, 0><<<dim3(6, 32), 256, 0, stream>>>(
            mlp, W2_t + (size_t)l * 768 * 3072, b2 + l * 768, x, x, nullptr, 4096, 768, 3072);
    }

    ln_kernel<<<1024, 256, 0, stream>>>(x, lnfg, lnfb, hbuf);
    gemm_lm<1><<<dim3(250, 16), 512, 0, stream>>>(
        hbuf, lm_t, lmb, (float*)d_out, 4096, 32000, 768);
}

// Round 15
// 1368.186 us; speedup vs baseline: 1.0263x; 1.0263x over previous
//
#include <hip/hip_runtime.h>
#include <hip/hip_bf16.h>
#include <cstdint>
#include <cstddef>

// ---------------------------------------------------------------------------
// GPT-2-small forward on MI355X. bf16 MFMA GEMMs (f32 accum), f32 residual
// stream. Weights repacked bf16 TRANSPOSED ([N][K]).
// gemm_bt: 128x128 BK64 single-buffer, XOR swizzle, 4 blocks/CU (layer GEMMs).
// gemm_lm: 256x128 BK64, 512 thr, 2 blocks/CU + full-line NT f32x4 epilogue.
//          (BK=32 falsified r14: occupancy is REGISTER-capped at 16 waves/CU
//          — 116 unified regs/wave — and 64B-stride rows defeat the swizzle.)
// attn   : block-cooperative K/V staging + causal load-balance qb swizzle.
// ---------------------------------------------------------------------------

typedef __bf16 bf16x8 __attribute__((ext_vector_type(8)));
typedef __bf16 bf16x4 __attribute__((ext_vector_type(4)));
typedef float  f32x4  __attribute__((ext_vector_type(4)));

#define MFMA16(a, b, c) __builtin_amdgcn_mfma_f32_16x16x32_bf16((a), (b), (c), 0, 0, 0)

__device__ __forceinline__ void g2l16(const void* g, void* l) {
    __builtin_amdgcn_global_load_lds(
        (const __attribute__((address_space(1))) void*)g,
        (__attribute__((address_space(3))) void*)l, 16, 0, 0);
}

// ---------------------------------------------------------------------------
// Weight repack: f32 [K,N] -> bf16 [N,K], 32x32 tiles, vectorized.
// ---------------------------------------------------------------------------
__global__ __launch_bounds__(256) void transpose_cvt(
    const float* __restrict__ src, __bf16* __restrict__ dst,
    int K, int N, int nNT)
{
    const float* s = src + (size_t)blockIdx.y * K * N;
    __bf16*      d = dst + (size_t)blockIdx.y * K * N;
    int kt = blockIdx.x / nNT, nt = blockIdx.x % nNT;
    int k0 = kt * 32, n0 = nt * 32;
    __shared__ float t[32][33];
    int rr = threadIdx.x >> 3, c4 = (threadIdx.x & 7) * 4;
    f32x4 v = *(const f32x4*)&s[(size_t)(k0 + rr) * N + n0 + c4];
#pragma unroll
    for (int j = 0; j < 4; j++) t[rr][c4 + j] = v[j];
    __syncthreads();
    bf16x4 ov;
#pragma unroll
    for (int j = 0; j < 4; j++) ov[j] = (__bf16)t[c4 + j][rr];
    *(bf16x4*)&d[(size_t)(n0 + rr) * K + k0 + c4] = ov;
}

// QKV gather-repack: Wq/Wk/Wv [L,H,768,64] f32 -> Wqkv_t [L][2304][768] bf16.
__global__ __launch_bounds__(256) void repack_qkv(
    const float* __restrict__ Wq, const float* __restrict__ Wk,
    const float* __restrict__ Wv, __bf16* __restrict__ dst)
{
    int l = blockIdx.z;
    int m = blockIdx.y / 12, h = blockIdx.y % 12;
    int kt = blockIdx.x / 2, nt = blockIdx.x % 2;
    const float* W = (m == 0 ? Wq : (m == 1 ? Wk : Wv)) + ((size_t)(l * 12 + h)) * 768 * 64;
    __bf16* d = dst + (size_t)l * 2304 * 768 + (size_t)(m * 768 + h * 64) * 768;
    int k0 = kt * 32, n0 = nt * 32;
    __shared__ float t[32][33];
    int rr = threadIdx.x >> 3, c4 = (threadIdx.x & 7) * 4;
    f32x4 v = *(const f32x4*)&W[(size_t)(k0 + rr) * 64 + n0 + c4];
#pragma unroll
    for (int j = 0; j < 4; j++) t[rr][c4 + j] = v[j];
    __syncthreads();
    bf16x4 ov;
#pragma unroll
    for (int j = 0; j < 4; j++) ov[j] = (__bf16)t[c4 + j][rr];
    *(bf16x4*)&d[(size_t)(n0 + rr) * 768 + k0 + c4] = ov;
}

// ---------------------------------------------------------------------------
// Embedding: wave-per-row, f32x4 vectorized.
// ---------------------------------------------------------------------------
__global__ __launch_bounds__(256) void embed_kernel(
    const int* __restrict__ idx, const float* __restrict__ tok,
    const float* __restrict__ pos, float* __restrict__ x)
{
    const int row = blockIdx.x * 4 + (threadIdx.x >> 6);
    const int lane = threadIdx.x & 63;
    int id = idx[row];
    const float* te = tok + (size_t)id * 768;
    const float* pe = pos + (size_t)(row & 1023) * 768;
    float* xr = x + (size_t)row * 768;
#pragma unroll
    for (int p = 0; p < 3; p++) {
        int c = p * 256 + lane * 4;
        f32x4 a = *(const f32x4*)&te[c];
        f32x4 b = *(const f32x4*)&pe[c];
        a[0] += b[0]; a[1] += b[1]; a[2] += b[2]; a[3] += b[3];
        *(f32x4*)&xr[c] = a;
    }
}

// ---------------------------------------------------------------------------
// LayerNorm: wave-per-row, f32x4 loads, bf16x4 stores, shuffle-only reduce.
// ---------------------------------------------------------------------------
__global__ __launch_bounds__(256) void ln_kernel(
    const float* __restrict__ x, const float* __restrict__ g,
    const float* __restrict__ bb, __bf16* __restrict__ out)
{
    const int row = blockIdx.x * 4 + (threadIdx.x >> 6);
    const int lane = threadIdx.x & 63;
    const float* xr = x + (size_t)row * 768;
    f32x4 v[3];
    float s = 0.f, s2 = 0.f;
#pragma unroll
    for (int p = 0; p < 3; p++) {
        v[p] = *(const f32x4*)&xr[p * 256 + lane * 4];
#pragma unroll
        for (int j = 0; j < 4; j++) { s += v[p][j]; s2 += v[p][j] * v[p][j]; }
    }
#pragma unroll
    for (int d = 1; d < 64; d <<= 1) {
        s  += __shfl_xor(s, d);
        s2 += __shfl_xor(s2, d);
    }
    float mean = s * (1.f / 768.f);
    float var  = s2 * (1.f / 768.f) - mean * mean;
    float rstd = rsqrtf(var + 1e-5f);
    __bf16* orow = out + (size_t)row * 768;
#pragma unroll
    for (int p = 0; p < 3; p++) {
        int c = p * 256 + lane * 4;
        f32x4 gg = *(const f32x4*)&g[c];
        f32x4 bv = *(const f32x4*)&bb[c];
        bf16x4 ov;
#pragma unroll
        for (int j = 0; j < 4; j++)
            ov[j] = (__bf16)((v[p][j] - mean) * rstd * gg[j] + bv[j]);
        *(bf16x4*)&orow[c] = ov;
    }
}

// ---------------------------------------------------------------------------
// gemm_bt: 128x128 tile, BK=64, 4 waves, single-buffered 32KB LDS, XOR chunk
// swizzle (0 conflicts), (256,4) — best measured config for layer GEMMs.
// ---------------------------------------------------------------------------
template <int RELU, int BIAS, int RES, int OBF16, int VT>
__global__ __launch_bounds__(256, 4) void gemm_bt(
    const __bf16* __restrict__ A, const __bf16* __restrict__ Bt,
    const float* __restrict__ bias, const float* __restrict__ res,
    void* __restrict__ Cout, __bf16* __restrict__ vt, int M, int N, int K)
{
    __shared__ __bf16 As[128 * 64];
    __shared__ __bf16 Bs[128 * 64];
    const int tid = threadIdx.x;
    const int w = tid >> 6, lane = tid & 63, lr = lane & 15, lg = lane >> 4;
    const int wr = w >> 1, wc = w & 1;

    const int MT  = gridDim.y;
    const int nwg = gridDim.x * gridDim.y;
    const int ord = blockIdx.y * gridDim.x + blockIdx.x;
    const int qq = nwg >> 3, rm = nwg & 7;
    const int xcd = ord & 7, pos = ord >> 3;
    const int wgid = (xcd < rm ? xcd * (qq + 1) : rm * (qq + 1) + (xcd - rm) * qq) + pos;
    const int m0 = (wgid % MT) * 128, n0 = (wgid / MT) * 128;

    f32x4 acc[4][4];
#pragma unroll
    for (int i = 0; i < 4; i++)
#pragma unroll
        for (int j = 0; j < 4; j++) acc[i][j] = (f32x4){0.f, 0.f, 0.f, 0.f};

    const __bf16* Abase = A  + (size_t)m0 * K;
    const __bf16* Bbase = Bt + (size_t)n0 * K;

    for (int k0 = 0; k0 < K; k0 += 64) {
#pragma unroll
        for (int u = 0; u < 4; ++u) {
            int chunk = u * 256 + tid;
            int rr = chunk >> 3, cc = chunk & 7;
            int se = (cc ^ (rr & 7)) << 3;
            g2l16(Abase + (size_t)rr * K + k0 + se, (char*)As + chunk * 16);
            g2l16(Bbase + (size_t)rr * K + k0 + se, (char*)Bs + chunk * 16);
        }
        __syncthreads();
#pragma unroll
        for (int ks = 0; ks < 2; ++ks) {
            bf16x8 af[4], bfv[4];
#pragma unroll
            for (int i = 0; i < 4; ++i) {
                int ra = wr * 64 + i * 16 + lr;
                af[i]  = *(const bf16x8*)((const char*)As + ra * 128 + (((ks * 4 + lg) ^ (ra & 7)) << 4));
                int rb = wc * 64 + i * 16 + lr;
                bfv[i] = *(const bf16x8*)((const char*)Bs + rb * 128 + (((ks * 4 + lg) ^ (rb & 7)) << 4));
            }
#pragma unroll
            for (int i = 0; i < 4; ++i)
#pragma unroll
                for (int j = 0; j < 4; ++j)
                    acc[i][j] = MFMA16(af[i], bfv[j], acc[i][j]);
        }
        __syncthreads();
    }

    const bool isv = VT && (n0 >= 1536);
#pragma unroll
    for (int i = 0; i < 4; i++) {
        int row = m0 + wr * 64 + i * 16 + lg * 4;
#pragma unroll
        for (int j = 0; j < 4; j++) {
            int col = n0 + wc * 64 + j * 16 + lr;
            if (isv) {   // write V transposed: vt[(b*12+h)*64+hs][t]
                int bb = row >> 10, tl = row & 1023;
                int vrow = (bb * 12 + ((col - 1536) >> 6)) * 64 + (col & 63);
                bf16x4 pv;
#pragma unroll
                for (int rr = 0; rr < 4; ++rr) pv[rr] = (__bf16)(acc[i][j][rr]);
                *(bf16x4*)&vt[(size_t)vrow * 1024 + tl] = pv;
            } else {
                float bv = BIAS ? bias[col] : 0.f;
#pragma unroll
                for (int rr = 0; rr < 4; rr++) {
                    float v = acc[i][j][rr] + bv;
                    if (RES)  v += res[(size_t)(row + rr) * N + col];
                    if (RELU) v = fmaxf(v, 0.f);
                    if (OBF16) ((__bf16*)Cout)[(size_t)(row + rr) * N + col] = (__bf16)v;
                    else       ((float*)Cout)[(size_t)(row + rr) * N + col] = v;
                }
            }
        }
    }
}

// ---------------------------------------------------------------------------
// gemm_lm: 256x128 tile, BK=64, 512 threads, 48KB LDS, XOR swizzle,
// 2 blocks/CU (register-capped: 16 waves/CU max at 116 regs/wave),
// full-line NT epilogue (r12/r13 validated: FETCH -110MB, WRITE clean).
// ---------------------------------------------------------------------------
template <int BIAS>
__global__ __launch_bounds__(512, 4) void gemm_lm(
    const __bf16* __restrict__ A, const __bf16* __restrict__ Bt,
    const float* __restrict__ bias, float* __restrict__ C, int M, int N, int K)
{
    __shared__ __bf16 S[(256 + 128) * 64];      // As | Bs, 48KB (also epi scratch)
    __bf16* As = S;
    __bf16* Bs = S + 256 * 64;
    const int tid = threadIdx.x;
    const int w = tid >> 6, lane = tid & 63, lr = lane & 15, lg = lane >> 4;
    const int wm = w >> 1, wn = w & 1;

    const int MT  = gridDim.y;
    const int nwg = gridDim.x * gridDim.y;
    const int ord = blockIdx.y * gridDim.x + blockIdx.x;
    const int qq = nwg >> 3, rm = nwg & 7;
    const int xcd = ord & 7, pos = ord >> 3;
    const int wgid = (xcd < rm ? xcd * (qq + 1) : rm * (qq + 1) + (xcd - rm) * qq) + pos;
    const int m0 = (wgid % MT) * 256, n0 = (wgid / MT) * 128;

    f32x4 acc[4][4];
#pragma unroll
    for (int i = 0; i < 4; i++)
#pragma unroll
        for (int j = 0; j < 4; j++) acc[i][j] = (f32x4){0.f, 0.f, 0.f, 0.f};

    const __bf16* Abase = A  + (size_t)m0 * K;
    const __bf16* Bbase = Bt + (size_t)n0 * K;

    for (int k0 = 0; k0 < K; k0 += 64) {
#pragma unroll
        for (int u = 0; u < 4; ++u) {
            int chunk = u * 512 + tid;
            int rr = chunk >> 3, cc = chunk & 7;
            g2l16(Abase + (size_t)rr * K + k0 + ((cc ^ (rr & 7)) << 3),
                  (char*)As + chunk * 16);
        }
#pragma unroll
        for (int u = 0; u < 2; ++u) {
            int chunk = u * 512 + tid;
            int rr = chunk >> 3, cc = chunk & 7;
            g2l16(Bbase + (size_t)rr * K + k0 + ((cc ^ (rr & 7)) << 3),
                  (char*)Bs + chunk * 16);
        }
        __syncthreads();
#pragma unroll
        for (int ks = 0; ks < 2; ++ks) {
            bf16x8 af[4], bfv[4];
#pragma unroll
            for (int i = 0; i < 4; ++i) {
                int ra = wm * 64 + i * 16 + lr;
                af[i]  = *(const bf16x8*)((const char*)As + ra * 128 + (((ks * 4 + lg) ^ (ra & 7)) << 4));
                int rb = wn * 64 + i * 16 + lr;
                bfv[i] = *(const bf16x8*)((const char*)Bs + rb * 128 + (((ks * 4 + lg) ^ (rb & 7)) << 4));
            }
#pragma unroll
            for (int i = 0; i < 4; ++i)
#pragma unroll
                for (int j = 0; j < 4; ++j)
                    acc[i][j] = MFMA16(af[i], bfv[j], acc[i][j]);
        }
        __syncthreads();            // all LDS reads done before scratch reuse
    }

    // ---- full-line NT epilogue: wave-private 16x72 f32 scratch ----
    float* wls = (float*)S + w * 1152;
    const int er = lane >> 4;                   // 4 rows per store instr
    const int ec = lane & 15;                   // 16 lanes x f32x4 = 2 full lines
    f32x4 bb4 = (f32x4){0.f, 0.f, 0.f, 0.f};
    if (BIAS) bb4 = *(const f32x4*)&bias[n0 + wn * 64 + ec * 4];
#pragma unroll
    for (int i = 0; i < 4; i++) {
#pragma unroll
        for (int j = 0; j < 4; j++)
#pragma unroll
            for (int rr = 0; rr < 4; rr++)
                wls[(lg * 4 + rr) * 72 + j * 16 + lr] = acc[i][j][rr];
#pragma unroll
        for (int t = 0; t < 4; t++) {
            int r16 = t * 4 + er;
            f32x4 v = *(const f32x4*)&wls[r16 * 72 + ec * 4];
            v[0] += bb4[0]; v[1] += bb4[1]; v[2] += bb4[2]; v[3] += bb4[3];
            int grow = m0 + wm * 64 + i * 16 + r16;
            __builtin_nontemporal_store(v, (f32x4*)(C + (size_t)grow * N + n0 + wn * 64 + ec * 4));
        }
    }
}

// ---------------------------------------------------------------------------
// Fused causal flash attention, block-cooperative K/V staging, fixed-max
// softmax (validated r5-r13). KVBLK=128, XOR-swizzled LDS, 3 blocks/CU,
// causal load-balance qb swizzle {x, 15-x, x^8} (r13, validated).
// ---------------------------------------------------------------------------
__global__ __launch_bounds__(256, 3) void attn_kernel(
    const __bf16* __restrict__ qkv, const __bf16* __restrict__ vt,
    __bf16* __restrict__ o)
{
    __shared__ __bf16 Kl[128 * 64];
    __shared__ __bf16 Vl[64 * 128];
    __shared__ __bf16 Pl[4][16][72];
    const int h = blockIdx.y, b = blockIdx.z;
    const int flat = blockIdx.x + 16 * (blockIdx.y + 12 * blockIdx.z);
    const int rch = flat >> 8;
    const int xq = blockIdx.x;
    const int qb = (rch == 0) ? xq : (rch == 1 ? 15 - xq : (xq ^ 8));
    const int tid = threadIdx.x, w = tid >> 6, lane = tid & 63, lr = lane & 15, lg = lane >> 4;
    const int q0 = qb * 64 + w * 16;
    const size_t rowb = (size_t)b * 1024;
    const __bf16* Kg = qkv + rowb * 2304 + 768 + (size_t)h * 64;
    const __bf16* Vg = vt + (size_t)(b * 12 + h) * 64 * 1024;

    bf16x8 qf[2];
    {
        const __bf16* qp = qkv + (rowb + q0 + lr) * 2304 + h * 64 + lg * 8;
        qf[0] = *(const bf16x8*)qp;
        qf[1] = *(const bf16x8*)(qp + 32);
    }

    f32x4 oacc[4];
#pragma unroll
    for (int i = 0; i < 4; i++) oacc[i] = (f32x4){0.f, 0.f, 0.f, 0.f};
    float lpart[4] = {0.f, 0.f, 0.f, 0.f};

    const int nkb = (qb >> 1) + 1;
    for (int kb = 0; kb < nkb; ++kb) {
        __syncthreads();
#pragma unroll
        for (int u = 0; u < 4; ++u) {
            int chunk = u * 256 + tid;
            int kr = chunk >> 3, cc = chunk & 7;
            g2l16(Kg + (size_t)(kb * 128 + kr) * 2304 + ((cc ^ (kr & 7)) << 3),
                  (char*)Kl + chunk * 16);
        }
#pragma unroll
        for (int u = 0; u < 4; ++u) {
            int chunk = u * 256 + tid;
            int vr = chunk >> 4, cc = chunk & 15;
            g2l16(Vg + (size_t)vr * 1024 + kb * 128 + ((cc ^ (vr & 15)) << 3),
                  (char*)Vl + chunk * 16);
        }
        __syncthreads();

#pragma unroll
        for (int hh = 0; hh < 2; ++hh) {
            if (kb * 128 + hh * 64 > q0 + 15) break;
            float e[4][4];
#pragma unroll
            for (int cb = 0; cb < 4; ++cb) {
                const int krow = hh * 64 + cb * 16 + lr;
                const int key  = kb * 128 + krow;
                bf16x8 k0 = *(const bf16x8*)((const char*)Kl + krow * 128 + ((lg ^ (krow & 7)) << 4));
                bf16x8 k1 = *(const bf16x8*)((const char*)Kl + krow * 128 + (((4 + lg) ^ (krow & 7)) << 4));
                f32x4 s = (f32x4){0.f, 0.f, 0.f, 0.f};
                s = MFMA16(qf[0], k0, s);
                s = MFMA16(qf[1], k1, s);
#pragma unroll
                for (int rr = 0; rr < 4; rr++) {
                    int qrow = q0 + lg * 4 + rr;
                    float p = (key > qrow) ? -1e30f : s[rr] * 0.125f;
                    e[cb][rr] = __expf(p - 3.0f);
                }
            }
#pragma unroll
            for (int rr = 0; rr < 4; rr++) {
                lpart[rr] += (e[0][rr] + e[1][rr]) + (e[2][rr] + e[3][rr]);
                Pl[w][lg * 4 + rr][lr]      = (__bf16)e[0][rr];
                Pl[w][lg * 4 + rr][16 + lr] = (__bf16)e[1][rr];
                Pl[w][lg * 4 + rr][32 + lr] = (__bf16)e[2][rr];
                Pl[w][lg * 4 + rr][48 + lr] = (__bf16)e[3][rr];
            }
            bf16x8 pf0 = *(const bf16x8*)&Pl[w][lr][lg * 8];
            bf16x8 pf1 = *(const bf16x8*)&Pl[w][lr][32 + lg * 8];
#pragma unroll
            for (int nb = 0; nb < 4; nb++) {
                const int vrow = nb * 16 + lr;
                bf16x8 v0 = *(const bf16x8*)((const char*)Vl + vrow * 256 + (((hh * 8 + lg) ^ (vrow & 15)) << 4));
                bf16x8 v1 = *(const bf16x8*)((const char*)Vl + vrow * 256 + (((hh * 8 + 4 + lg) ^ (vrow & 15)) << 4));
                oacc[nb] = MFMA16(pf0, v0, oacc[nb]);
                oacc[nb] = MFMA16(pf1, v1, oacc[nb]);
            }
        }
    }

#pragma unroll
    for (int rr = 0; rr < 4; rr++) {
        float ls = lpart[rr];
        ls += __shfl_xor(ls, 1);
        ls += __shfl_xor(ls, 2);
        ls += __shfl_xor(ls, 4);
        ls += __shfl_xor(ls, 8);
        float inv = 1.0f / ls;
        size_t row = rowb + q0 + lg * 4 + rr;
#pragma unroll
        for (int nb = 0; nb < 4; nb++)
            o[row * 768 + h * 64 + nb * 16 + lr] = (__bf16)(oacc[nb][rr] * inv);
    }
}

// ---------------------------------------------------------------------------
extern "C" void kernel_launch(void* const* d_in, const int* in_sizes, int n_in,
                              void* d_out, int out_size, void* d_ws, size_t ws_size,
                              hipStream_t stream)
{
    (void)in_sizes; (void)n_in; (void)out_size; (void)ws_size;
    const int*   idx  = (const int*)d_in[0];
    const float* tok  = (const float*)d_in[1];
    const float* pos  = (const float*)d_in[2];
    const float* Wq   = (const float*)d_in[3];
    const float* Wk   = (const float*)d_in[4];
    const float* Wv   = (const float*)d_in[5];
    const float* Wp   = (const float*)d_in[6];
    const float* bp   = (const float*)d_in[7];
    const float* ln1g = (const float*)d_in[8];
    const float* ln1b = (const float*)d_in[9];
    const float* ln2g = (const float*)d_in[10];
    const float* ln2b = (const float*)d_in[11];
    const float* W1   = (const float*)d_in[12];
    const float* b1   = (const float*)d_in[13];
    const float* W2   = (const float*)d_in[14];
    const float* b2   = (const float*)d_in[15];
    const float* lnfg = (const float*)d_in[16];
    const float* lnfb = (const float*)d_in[17];
    const float* lmW  = (const float*)d_in[18];
    const float* lmb  = (const float*)d_in[19];

    char* ws = (char*)d_ws;
    size_t off = 0;
    auto alloc = [&](size_t bytes) {
        char* p = ws + off;
        off += (bytes + 255) & ~(size_t)255;
        return p;
    };
    __bf16* Wqkv_t = (__bf16*)alloc((size_t)6 * 2304 * 768 * 2);
    __bf16* Wp_t   = (__bf16*)alloc((size_t)6 * 768 * 768 * 2);
    __bf16* W1_t   = (__bf16*)alloc((size_t)6 * 3072 * 768 * 2);
    __bf16* W2_t   = (__bf16*)alloc((size_t)6 * 768 * 3072 * 2);
    __bf16* lm_t   = (__bf16*)alloc((size_t)32000 * 768 * 2);
    float*  x      = (float*)alloc((size_t)4096 * 768 * 4);
    __bf16* hbuf   = (__bf16*)alloc((size_t)4096 * 768 * 2);
    __bf16* qkv    = (__bf16*)alloc((size_t)4096 * 2304 * 2);
    __bf16* obuf   = (__bf16*)alloc((size_t)4096 * 768 * 2);
    __bf16* mlp    = (__bf16*)alloc((size_t)4096 * 3072 * 2);
    __bf16* vt     = mlp;   // lifetime-disjoint: vt used qkv->attn, mlp fc1->fc2

    // ---- weight repack (bf16, transposed) ----
    transpose_cvt<<<dim3(24 * 24, 6), 256, 0, stream>>>(Wp, Wp_t, 768, 768, 24);
    transpose_cvt<<<dim3(24 * 96, 6), 256, 0, stream>>>(W1, W1_t, 768, 3072, 96);
    transpose_cvt<<<dim3(96 * 24, 6), 256, 0, stream>>>(W2, W2_t, 3072, 768, 24);
    transpose_cvt<<<dim3(24 * 1000, 1), 256, 0, stream>>>(lmW, lm_t, 768, 32000, 1000);
    repack_qkv<<<dim3(48, 36, 6), 256, 0, stream>>>(Wq, Wk, Wv, Wqkv_t);

    // ---- forward ----
    embed_kernel<<<1024, 256, 0, stream>>>(idx, tok, pos, x);

    for (int l = 0; l < 6; l++) {
        ln_kernel<<<1024, 256, 0, stream>>>(x, ln1g + l * 768, ln1b + l * 768, hbuf);
        gemm_bt<0, 0, 0, 1, 1><<<dim3(18, 32), 256, 0, stream>>>(
            hbuf, Wqkv_t + (size_t)l * 2304 * 768, nullptr, nullptr, qkv, vt, 4096, 2304, 768);
        attn_kernel<<<dim3(16, 12, 4), 256, 0, stream>>>(qkv, vt, obuf);
        gemm_bt<0, 1, 1, 0, 0><<<dim3(6, 32), 256, 0, stream>>>(
            obuf, Wp_t + (size_t)l * 768 * 768, bp + l * 768, x, x, nullptr, 4096, 768, 768);
        ln_kernel<<<1024, 256, 0, stream>>>(x, ln2g + l * 768, ln2b + l * 768, hbuf);
        gemm_bt<1, 1, 0, 1, 0><<<dim3(24, 32), 256, 0, stream>>>(
            hbuf, W1_t + (size_t)l * 3072 * 768, b1 + l * 3072, nullptr, mlp, nullptr, 4096, 3072, 768);
        gemm_bt<0, 1, 1, 0, 0><<<dim3(6, 32), 256, 0, stream>>>(
            mlp, W2_t + (size_t)l * 768 * 3072, b2 + l * 768, x, x, nullptr, 4096, 768, 3072);
    }

    ln_kernel<<<1024, 256, 0, stream>>>(x, lnfg, lnfb, hbuf);
    gemm_lm<1><<<dim3(250, 16), 512, 0, stream>>>(
        hbuf, lm_t, lmb, (float*)d_out, 4096, 32000, 768);
}